// Round 3
// baseline (2263.054 us; speedup 1.0000x reference)
//
#include <hip/hip_runtime.h>

// Hetero GraphSAGE (3 layers, users<->movies) + JK-cat projection + BN-MLP edge scorer.
// R3 = R2 structure with the cls2 grid-truncation bug fixed (500000/256 != integer).
//   - Uniform-row GEMMs: 1-wave blocks, lane = output column, 16 rows per wave;
//     row addresses wave-uniform -> s_load, weights per-lane coalesced -> v_fmac.
//     No LDS, no bank conflicts.
//   - BN1 stats fused in cls1 (lane=col); BN2 stats via separate small pass.

namespace {

constexpr int NUc = 100000;
constexpr int NMc = 20000;
constexpr int HD  = 64;
constexpr int NE  = 1000000;
constexpr int ELc = 500000;
constexpr int NL  = 3;
constexpr float BN_EPS = 1e-5f;

constexpr int RU = 16;   // rows per wave in uniform-row GEMM kernels

// ---------------- CSR build ----------------

__global__ void count_kernel(const int* __restrict__ eu, const int* __restrict__ em,
                             int* __restrict__ cu, int* __restrict__ cm) {
  int t = blockIdx.x * 256 + threadIdx.x;
  if (t < NE) {
    atomicAdd(&cu[eu[t]], 1);
    atomicAdd(&cm[em[t]], 1);
  }
}

__global__ void scan_kernel(const int* __restrict__ cnt, int n, int* __restrict__ offs) {
  __shared__ int sums[1024];
  int t = threadIdx.x;
  int seg = (n + 1023) >> 10;
  int lo = t * seg;
  int hi = min(lo + seg, n);
  int s = 0;
  for (int i = lo; i < hi; i++) s += cnt[i];
  sums[t] = s;
  __syncthreads();
  for (int d = 1; d < 1024; d <<= 1) {
    int v  = sums[t];
    int vp = (t >= d) ? sums[t - d] : 0;
    __syncthreads();
    sums[t] = v + vp;
    __syncthreads();
  }
  int run = (t > 0) ? sums[t - 1] : 0;
  for (int i = lo; i < hi; i++) { offs[i] = run; run += cnt[i]; }
  if (t == 1023) offs[n] = sums[1023];
}

__global__ void binscatter_kernel(const int* __restrict__ eu, const int* __restrict__ em,
                                  int* __restrict__ cu, int* __restrict__ cm,
                                  int* __restrict__ su, int* __restrict__ sm) {
  int t = blockIdx.x * 256 + threadIdx.x;
  if (t < NE) {
    int u = eu[t], m = em[t];
    int pm = atomicAdd(&cm[m], 1); sm[pm] = u;
    int pu = atomicAdd(&cu[u], 1); su[pu] = m;
  }
}

__global__ void gather_xu0_kernel(const int* __restrict__ n_id, const float* __restrict__ emb,
                                  float* __restrict__ xu0) {
  int t = blockIdx.x * 256 + threadIdx.x;
  if (t < NUc * 16) {
    int n = t >> 4, c = t & 15;
    float4 v = *(const float4*)(emb + (size_t)n_id[n] * HD + c * 4);
    *(float4*)(xu0 + (size_t)n * HD + c * 4) = v;
  }
}

// ---------------- mean aggregation: one wave per dst node, lane = feature ----------------

__global__ void aggregate_kernel(const int* __restrict__ offs, const int* __restrict__ ssrc,
                                 const float* __restrict__ xsrc, int xstride,
                                 float* __restrict__ agg, int ndst) {
  int gid  = blockIdx.x * 256 + threadIdx.x;
  int w    = gid >> 6;
  int lane = gid & 63;
  if (w >= ndst) return;
  int s0 = offs[w], s1 = offs[w + 1];
  float acc = 0.f;
  int i = s0;
  for (; i + 4 <= s1; i += 4) {
    int a0 = ssrc[i], a1 = ssrc[i + 1], a2 = ssrc[i + 2], a3 = ssrc[i + 3];
    acc += xsrc[(size_t)a0 * xstride + lane] + xsrc[(size_t)a1 * xstride + lane] +
           xsrc[(size_t)a2 * xstride + lane] + xsrc[(size_t)a3 * xstride + lane];
  }
  for (; i < s1; i++) acc += xsrc[(size_t)ssrc[i] * xstride + lane];
  float inv = 1.f / fmaxf((float)(s1 - s0), 1.f);
  agg[(size_t)w * HD + lane] = acc * inv;
}

// ---------------- uniform-row GEMM core ----------------
// acc[r] += sum_k x[r][k] * W[k*64 + lane]; x addresses wave-uniform -> s_load.

__device__ __forceinline__ void mm_block(const float* const (&rowp)[RU],
                                         const float* __restrict__ W, int K,
                                         int lane, float (&acc)[RU]) {
  for (int k = 0; k < K; k += 4) {
    float w0 = W[(k + 0) * 64 + lane];
    float w1 = W[(k + 1) * 64 + lane];
    float w2 = W[(k + 2) * 64 + lane];
    float w3 = W[(k + 3) * 64 + lane];
#pragma unroll
    for (int r = 0; r < RU; r++) {
      const float* xr = rowp[r] + k;
      acc[r] = fmaf(xr[0], w0, acc[r]);
      acc[r] = fmaf(xr[1], w1, acc[r]);
      acc[r] = fmaf(xr[2], w2, acc[r]);
      acc[r] = fmaf(xr[3], w3, acc[r]);
    }
  }
}

// out = relu(agg@Wl + x@Wr + b)
__global__ __launch_bounds__(64) void sage_u_kernel(
    int N, const float* __restrict__ agg,
    const float* __restrict__ xin, int xstride,
    const float* __restrict__ Wl, const float* __restrict__ Wr,
    const float* __restrict__ bias,
    float* __restrict__ out, int ostride) {
  int lane = threadIdx.x;
  int base = blockIdx.x * RU;
  float acc[RU] = {};
  const float* rowp[RU];
#pragma unroll
  for (int r = 0; r < RU; r++) rowp[r] = agg + (size_t)(base + r) * HD;
  mm_block(rowp, Wl, 64, lane, acc);
#pragma unroll
  for (int r = 0; r < RU; r++) rowp[r] = xin + (size_t)(base + r) * xstride;
  mm_block(rowp, Wr, 64, lane, acc);
  float b = bias[lane];
#pragma unroll
  for (int r = 0; r < RU; r++)
    out[(size_t)(base + r) * ostride + lane] = fmaxf(acc[r] + b, 0.f);
}

// h = x(JK-cat, stride 192) @ W + b
__global__ __launch_bounds__(64) void proj_u_kernel(
    int N, const float* __restrict__ xin, const float* __restrict__ W,
    const float* __restrict__ bias, float* __restrict__ out) {
  int lane = threadIdx.x;
  int base = blockIdx.x * RU;
  float acc[RU] = {};
  const float* rowp[RU];
#pragma unroll
  for (int r = 0; r < RU; r++) rowp[r] = xin + (size_t)(base + r) * (NL * HD);
  mm_block(rowp, W, NL * HD, lane, acc);
  float b = bias[lane];
#pragma unroll
  for (int r = 0; r < RU; r++)
    out[(size_t)(base + r) * HD + lane] = acc[r] + b;
}

// y1 = cat(h_u[lu], h_m[lm]) @ W1 + b1 ; fused BN1 column sums (lane = column)
__global__ __launch_bounds__(64) void cls1_u_kernel(
    const float* __restrict__ hu, const float* __restrict__ hm,
    const int* __restrict__ lu, const int* __restrict__ lm,
    const float* __restrict__ W1, const float* __restrict__ b1,
    float* __restrict__ y1, float* __restrict__ sum1, float* __restrict__ ssq1) {
  int lane = threadIdx.x;
  int base = blockIdx.x * RU;
  float acc[RU] = {};
  const float* rowp[RU];
#pragma unroll
  for (int r = 0; r < RU; r++) rowp[r] = hu + (size_t)lu[base + r] * HD;
  mm_block(rowp, W1, 64, lane, acc);
#pragma unroll
  for (int r = 0; r < RU; r++) rowp[r] = hm + (size_t)lm[base + r] * HD;
  mm_block(rowp, W1 + 64 * 64, 64, lane, acc);
  float b = b1[lane];
  float s = 0.f, ss = 0.f;
#pragma unroll
  for (int r = 0; r < RU; r++) {
    float v = acc[r] + b;
    y1[(size_t)(base + r) * HD + lane] = v;
    s += v;
    ss += v * v;
  }
  atomicAdd(&sum1[lane], s);
  atomicAdd(&ssq1[lane], ss);
}

__global__ void bn_finalize_kernel(const float* __restrict__ sum, const float* __restrict__ ssq,
                                   const float* __restrict__ g, const float* __restrict__ be,
                                   int ncols, float inv_n,
                                   float* __restrict__ scale, float* __restrict__ shift) {
  int t = threadIdx.x;
  if (t < ncols) {
    float m = sum[t] * inv_n;
    float v = ssq[t] * inv_n - m * m;   // biased variance, as torch BN training-mode
    float rstd = rsqrtf(v + BN_EPS);
    float sc = g[t] * rstd;
    scale[t] = sc;
    shift[t] = be[t] - m * sc;
  }
}

// y2 = relu(BN1(y1)) @ W2 + b2 ; thread = row, weights scalarized (uniform loads)
__global__ __launch_bounds__(256) void cls2_kernel(
    const float* __restrict__ y1, const float* __restrict__ scale1,
    const float* __restrict__ shift1, const float* __restrict__ W2,
    const float* __restrict__ b2, float* __restrict__ y2) {
  int r = blockIdx.x * 256 + threadIdx.x;
  if (r >= ELc) return;   // R3 fix: 500000 % 256 != 0 -> round-up grid + guard
  const float* xr = y1 + (size_t)r * HD;
  float acc[32] = {};
  for (int k = 0; k < 64; k += 4) {
    float4 v = *(const float4*)(xr + k);
    float x0 = fmaxf(v.x * scale1[k + 0] + shift1[k + 0], 0.f);
    float x1 = fmaxf(v.y * scale1[k + 1] + shift1[k + 1], 0.f);
    float x2 = fmaxf(v.z * scale1[k + 2] + shift1[k + 2], 0.f);
    float x3 = fmaxf(v.w * scale1[k + 3] + shift1[k + 3], 0.f);
#pragma unroll
    for (int h = 0; h < 32; h++) {
      acc[h] = fmaf(x0, W2[(k + 0) * 32 + h], acc[h]);
      acc[h] = fmaf(x1, W2[(k + 1) * 32 + h], acc[h]);
      acc[h] = fmaf(x2, W2[(k + 2) * 32 + h], acc[h]);
      acc[h] = fmaf(x3, W2[(k + 3) * 32 + h], acc[h]);
    }
  }
#pragma unroll
  for (int h = 0; h < 32; h += 4) {
    float4 o;
    o.x = acc[h + 0] + b2[h + 0];
    o.y = acc[h + 1] + b2[h + 1];
    o.z = acc[h + 2] + b2[h + 2];
    o.w = acc[h + 3] + b2[h + 3];
    *(float4*)(y2 + (size_t)r * 32 + h) = o;
  }
}

// column sums/sumsq of y2 [EL x 32] for BN2
__global__ __launch_bounds__(256) void stats32_kernel(const float* __restrict__ y2,
                                                      float* __restrict__ sum2,
                                                      float* __restrict__ ssq2) {
  __shared__ float ls[256], lss[256];
  int t = threadIdx.x;
  int col = t & 31, rg = t >> 5;  // 8 row-groups
  float s = 0.f, ss = 0.f;
  for (size_t row = (size_t)blockIdx.x * 8 + rg; row < ELc; row += (size_t)gridDim.x * 8) {
    float v = y2[row * 32 + col];
    s += v;
    ss += v * v;
  }
  ls[t] = s; lss[t] = ss;
  __syncthreads();
  if (rg == 0) {
    for (int g = 1; g < 8; g++) { s += ls[g * 32 + col]; ss += lss[g * 32 + col]; }
    atomicAdd(&sum2[col], s);
    atomicAdd(&ssq2[col], ss);
  }
}

// out = relu(BN2(y2)) @ W3 + b3
__global__ void cls3_kernel(const float* __restrict__ y2, const float* __restrict__ scale2,
                            const float* __restrict__ shift2, const float* __restrict__ W3,
                            const float* __restrict__ b3, float* __restrict__ outp) {
  int r = blockIdx.x * 256 + threadIdx.x;
  if (r >= ELc) return;
  float s = b3[0];
#pragma unroll
  for (int j = 0; j < 32; j++) {
    float v = y2[(size_t)r * 32 + j];
    v = fmaxf(v * scale2[j] + shift2[j], 0.f);
    s += v * W3[j];
  }
  outp[r] = s;
}

}  // namespace

extern "C" void kernel_launch(void* const* d_in, const int* in_sizes, int n_in,
                              void* d_out, int out_size, void* d_ws, size_t ws_size,
                              hipStream_t stream) {
  const int*   n_id    = (const int*)d_in[0];
  const float* movie_x = (const float*)d_in[1];
  const int*   eu      = (const int*)d_in[2];
  const int*   em      = (const int*)d_in[3];
  const int*   lu      = (const int*)d_in[4];
  const int*   lm      = (const int*)d_in[5];
  const float* uemb    = (const float*)d_in[6];
  const float* Wl_um   = (const float*)d_in[7];
  const float* b_um    = (const float*)d_in[8];
  const float* Wr_um   = (const float*)d_in[9];
  const float* Wl_mu   = (const float*)d_in[10];
  const float* b_mu    = (const float*)d_in[11];
  const float* Wr_mu   = (const float*)d_in[12];
  const float* puW     = (const float*)d_in[13];
  const float* pub     = (const float*)d_in[14];
  const float* pmW     = (const float*)d_in[15];
  const float* pmb     = (const float*)d_in[16];
  const float* W1      = (const float*)d_in[17];
  const float* b1      = (const float*)d_in[18];
  const float* g1      = (const float*)d_in[19];
  const float* be1     = (const float*)d_in[20];
  const float* W2      = (const float*)d_in[21];
  const float* b2      = (const float*)d_in[22];
  const float* g2      = (const float*)d_in[23];
  const float* be2     = (const float*)d_in[24];
  const float* W3      = (const float*)d_in[25];
  const float* b3      = (const float*)d_in[26];
  float* outp = (float*)d_out;

  float* ws = (float*)d_ws;
  size_t o = 0;
  float* xu0    = ws + o; o += (size_t)NUc * HD;        // 6.40M f
  float* outs_u = ws + o; o += (size_t)NUc * NL * HD;   // 19.20M f
  float* outs_m = ws + o; o += (size_t)NMc * NL * HD;   //  3.84M f
  float* agg_u  = ws + o; o += (size_t)NUc * HD;        //  6.40M f
  float* agg_m  = ws + o; o += (size_t)NMc * HD;        //  1.28M f (conv region = 37.12M f)
  float* y1 = ws;  // [EL][64] = 32M f, overlaps conv region (dead before cls1)
  float* y2     = ws + o; o += (size_t)ELc * 32;        // 16.00M f
  float* h_u    = ws + o; o += (size_t)NUc * HD;
  float* h_m    = ws + o; o += (size_t)NMc * HD;
  int* ssrc_u = (int*)(ws + o); o += NE;
  int* ssrc_m = (int*)(ws + o); o += NE;
  int* cnt_u  = (int*)(ws + o); o += NUc;
  int* cnt_m  = (int*)(ws + o); o += NMc;
  int* offs_u = (int*)(ws + o); o += NUc + 64;
  int* offs_m = (int*)(ws + o); o += NMc + 64;
  int* cur_u  = (int*)(ws + o); o += NUc;
  int* cur_m  = (int*)(ws + o); o += NMc;
  float* stats = ws + o; o += 512;
  if (ws_size < o * sizeof(float)) return;  // ws too small -> leave zeros (diagnostic)

  float* sum1 = stats,        *ssq1 = stats + 64;
  float* sum2 = stats + 128,  *ssq2 = stats + 160;
  float* scale1 = stats + 192, *shift1 = stats + 256;
  float* scale2 = stats + 320, *shift2 = stats + 352;

  hipMemsetAsync(cnt_u, 0, NUc * sizeof(int), stream);
  hipMemsetAsync(cnt_m, 0, NMc * sizeof(int), stream);
  hipMemsetAsync(stats, 0, 192 * sizeof(float), stream);

  int eb = (NE + 255) / 256;
  count_kernel<<<eb, 256, 0, stream>>>(eu, em, cnt_u, cnt_m);
  scan_kernel<<<1, 1024, 0, stream>>>(cnt_u, NUc, offs_u);
  scan_kernel<<<1, 1024, 0, stream>>>(cnt_m, NMc, offs_m);
  hipMemcpyAsync(cur_u, offs_u, NUc * sizeof(int), hipMemcpyDeviceToDevice, stream);
  hipMemcpyAsync(cur_m, offs_m, NMc * sizeof(int), hipMemcpyDeviceToDevice, stream);
  binscatter_kernel<<<eb, 256, 0, stream>>>(eu, em, cur_u, cur_m, ssrc_u, ssrc_m);
  gather_xu0_kernel<<<(NUc * 16 + 255) / 256, 256, 0, stream>>>(n_id, uemb, xu0);

  for (int i = 0; i < NL; i++) {
    const float* xu_prev = (i == 0) ? xu0 : (outs_u + (size_t)(i - 1) * HD);
    const float* xm_prev = (i == 0) ? movie_x : (outs_m + (size_t)(i - 1) * HD);
    int su = (i == 0) ? HD : NL * HD;
    int sm = (i == 0) ? HD : NL * HD;
    aggregate_kernel<<<(NMc * 64 + 255) / 256, 256, 0, stream>>>(offs_m, ssrc_m, xu_prev, su, agg_m, NMc);
    aggregate_kernel<<<(NUc * 64 + 255) / 256, 256, 0, stream>>>(offs_u, ssrc_u, xm_prev, sm, agg_u, NUc);
    sage_u_kernel<<<NMc / RU, 64, 0, stream>>>(
        NMc, agg_m, xm_prev, sm,
        Wl_um + (size_t)i * HD * HD, Wr_um + (size_t)i * HD * HD, b_um + (size_t)i * HD,
        outs_m + (size_t)i * HD, NL * HD);
    sage_u_kernel<<<NUc / RU, 64, 0, stream>>>(
        NUc, agg_u, xu_prev, su,
        Wl_mu + (size_t)i * HD * HD, Wr_mu + (size_t)i * HD * HD, b_mu + (size_t)i * HD,
        outs_u + (size_t)i * HD, NL * HD);
  }

  proj_u_kernel<<<NUc / RU, 64, 0, stream>>>(NUc, outs_u, puW, pub, h_u);
  proj_u_kernel<<<NMc / RU, 64, 0, stream>>>(NMc, outs_m, pmW, pmb, h_m);

  cls1_u_kernel<<<ELc / RU, 64, 0, stream>>>(h_u, h_m, lu, lm, W1, b1, y1, sum1, ssq1);
  bn_finalize_kernel<<<1, 64, 0, stream>>>(sum1, ssq1, g1, be1, 64, 1.f / ELc, scale1, shift1);
  cls2_kernel<<<(ELc + 255) / 256, 256, 0, stream>>>(y1, scale1, shift1, W2, b2, y2);
  stats32_kernel<<<1024, 256, 0, stream>>>(y2, sum2, ssq2);
  bn_finalize_kernel<<<1, 64, 0, stream>>>(sum2, ssq2, g2, be2, 32, 1.f / ELc, scale2, shift2);
  cls3_kernel<<<(ELc + 255) / 256, 256, 0, stream>>>(y2, scale2, shift2, W3, b3, outp);
}

// Round 4
// 1574.063 us; speedup vs baseline: 1.4377x; 1.4377x over previous
//
#include <hip/hip_runtime.h>

// Hetero GraphSAGE (3 layers, users<->movies) + JK-cat projection + BN-MLP edge scorer.
// R4: ALL dense GEMMs use the thread-per-row pattern (validated by cls2 in R2/R3):
//   thread = output row; acc[NOUT] static-indexed in VGPRs; x row via per-lane
//   float4 loads (deep outstanding-load capacity on the vector pipe); weight rows
//   uniform-address (L1/K$-hot, shared by all waves). The R3 "s_load the x rows"
//   pattern was latency-bound (VALUBusy 7.5%): random/strided scalar loads miss K$
//   and the scalar pipe can't hide them.
// BN stats via a separate streaming pass (y is L3-resident).

namespace {

constexpr int NUc = 100000;
constexpr int NMc = 20000;
constexpr int HD  = 64;
constexpr int NE  = 1000000;
constexpr int ELc = 500000;
constexpr int NL  = 3;
constexpr float BN_EPS = 1e-5f;

// ---------------- CSR build ----------------

__global__ void count_kernel(const int* __restrict__ eu, const int* __restrict__ em,
                             int* __restrict__ cu, int* __restrict__ cm) {
  int t = blockIdx.x * 256 + threadIdx.x;
  if (t < NE) {
    atomicAdd(&cu[eu[t]], 1);
    atomicAdd(&cm[em[t]], 1);
  }
}

__global__ void scan_kernel(const int* __restrict__ cnt, int n, int* __restrict__ offs) {
  __shared__ int sums[1024];
  int t = threadIdx.x;
  int seg = (n + 1023) >> 10;
  int lo = t * seg;
  int hi = min(lo + seg, n);
  int s = 0;
  for (int i = lo; i < hi; i++) s += cnt[i];
  sums[t] = s;
  __syncthreads();
  for (int d = 1; d < 1024; d <<= 1) {
    int v  = sums[t];
    int vp = (t >= d) ? sums[t - d] : 0;
    __syncthreads();
    sums[t] = v + vp;
    __syncthreads();
  }
  int run = (t > 0) ? sums[t - 1] : 0;
  for (int i = lo; i < hi; i++) { offs[i] = run; run += cnt[i]; }
  if (t == 1023) offs[n] = sums[1023];
}

__global__ void binscatter_kernel(const int* __restrict__ eu, const int* __restrict__ em,
                                  int* __restrict__ cu, int* __restrict__ cm,
                                  int* __restrict__ su, int* __restrict__ sm) {
  int t = blockIdx.x * 256 + threadIdx.x;
  if (t < NE) {
    int u = eu[t], m = em[t];
    int pm = atomicAdd(&cm[m], 1); sm[pm] = u;
    int pu = atomicAdd(&cu[u], 1); su[pu] = m;
  }
}

__global__ void gather_xu0_kernel(const int* __restrict__ n_id, const float* __restrict__ emb,
                                  float* __restrict__ xu0) {
  int t = blockIdx.x * 256 + threadIdx.x;
  if (t < NUc * 16) {
    int n = t >> 4, c = t & 15;
    float4 v = *(const float4*)(emb + (size_t)n_id[n] * HD + c * 4);
    *(float4*)(xu0 + (size_t)n * HD + c * 4) = v;
  }
}

// ---------------- mean aggregation: one wave per dst node, lane = feature ----------------

__global__ void aggregate_kernel(const int* __restrict__ offs, const int* __restrict__ ssrc,
                                 const float* __restrict__ xsrc, int xstride,
                                 float* __restrict__ agg, int ndst) {
  int gid  = blockIdx.x * 256 + threadIdx.x;
  int w    = gid >> 6;
  int lane = gid & 63;
  if (w >= ndst) return;
  int s0 = offs[w], s1 = offs[w + 1];
  float acc = 0.f;
  int i = s0;
  for (; i + 4 <= s1; i += 4) {
    int a0 = ssrc[i], a1 = ssrc[i + 1], a2 = ssrc[i + 2], a3 = ssrc[i + 3];
    acc += xsrc[(size_t)a0 * xstride + lane] + xsrc[(size_t)a1 * xstride + lane] +
           xsrc[(size_t)a2 * xstride + lane] + xsrc[(size_t)a3 * xstride + lane];
  }
  for (; i < s1; i++) acc += xsrc[(size_t)ssrc[i] * xstride + lane];
  float inv = 1.f / fmaxf((float)(s1 - s0), 1.f);
  agg[(size_t)w * HD + lane] = acc * inv;
}

// ---------------- thread-per-row GEMM core ----------------
// acc[h] += x[k] * W[k*NOUT + h]; x per-lane float4, W uniform (L1/K$-hot).
// k-loop NOT fully unrolled (keeps body ~2-4KB, I$-friendly); h-loop unrolled
// so acc[] is statically indexed and lives in VGPRs.

template <int KTOT, int NOUT>
__device__ __forceinline__ void row_mm(const float* __restrict__ x,
                                       const float* __restrict__ W,
                                       float (&acc)[NOUT]) {
#pragma unroll 2
  for (int k = 0; k < KTOT; k += 4) {
    float4 v = *(const float4*)(x + k);
    const float* w = W + k * NOUT;
#pragma unroll
    for (int h = 0; h < NOUT; h++) {
      acc[h] = fmaf(v.x, w[0 * NOUT + h], acc[h]);
      acc[h] = fmaf(v.y, w[1 * NOUT + h], acc[h]);
      acc[h] = fmaf(v.z, w[2 * NOUT + h], acc[h]);
      acc[h] = fmaf(v.w, w[3 * NOUT + h], acc[h]);
    }
  }
}

// out = relu(agg@Wl + x@Wr + b)
__global__ __launch_bounds__(256) void sage_kernel(
    int N, const float* __restrict__ agg,
    const float* __restrict__ xin, int xstride,
    const float* __restrict__ Wl, const float* __restrict__ Wr,
    const float* __restrict__ bias,
    float* __restrict__ out, int ostride) {
  int r = blockIdx.x * 256 + threadIdx.x;
  if (r >= N) return;
  float acc[64];
#pragma unroll
  for (int h = 0; h < 64; h++) acc[h] = bias[h];
  row_mm<64, 64>(agg + (size_t)r * HD, Wl, acc);
  row_mm<64, 64>(xin + (size_t)r * xstride, Wr, acc);
  float* o = out + (size_t)r * ostride;
#pragma unroll
  for (int h = 0; h < 64; h += 4) {
    float4 v;
    v.x = fmaxf(acc[h + 0], 0.f);
    v.y = fmaxf(acc[h + 1], 0.f);
    v.z = fmaxf(acc[h + 2], 0.f);
    v.w = fmaxf(acc[h + 3], 0.f);
    *(float4*)(o + h) = v;
  }
}

// h = x(JK-cat, stride 192) @ W + b
__global__ __launch_bounds__(256) void proj_kernel(
    int N, const float* __restrict__ xin, const float* __restrict__ W,
    const float* __restrict__ bias, float* __restrict__ out) {
  int r = blockIdx.x * 256 + threadIdx.x;
  if (r >= N) return;
  float acc[64];
#pragma unroll
  for (int h = 0; h < 64; h++) acc[h] = bias[h];
  row_mm<192, 64>(xin + (size_t)r * (NL * HD), W, acc);
  float* o = out + (size_t)r * HD;
#pragma unroll
  for (int h = 0; h < 64; h += 4)
    *(float4*)(o + h) = make_float4(acc[h], acc[h + 1], acc[h + 2], acc[h + 3]);
}

// y1 = cat(h_u[lu], h_m[lm]) @ W1 + b1
__global__ __launch_bounds__(256) void cls1_kernel(
    const float* __restrict__ hu, const float* __restrict__ hm,
    const int* __restrict__ lu, const int* __restrict__ lm,
    const float* __restrict__ W1, const float* __restrict__ b1,
    float* __restrict__ y1) {
  int r = blockIdx.x * 256 + threadIdx.x;
  if (r >= ELc) return;
  float acc[64];
#pragma unroll
  for (int h = 0; h < 64; h++) acc[h] = b1[h];
  row_mm<64, 64>(hu + (size_t)lu[r] * HD, W1, acc);
  row_mm<64, 64>(hm + (size_t)lm[r] * HD, W1 + 64 * 64, acc);
  float* o = y1 + (size_t)r * HD;
#pragma unroll
  for (int h = 0; h < 64; h += 4)
    *(float4*)(o + h) = make_float4(acc[h], acc[h + 1], acc[h + 2], acc[h + 3]);
}

// column sums/sumsq of y [nrows x C]
template <int C>
__global__ __launch_bounds__(256) void stats_kernel(const float* __restrict__ y, int nrows,
                                                    float* __restrict__ sum,
                                                    float* __restrict__ ssq) {
  constexpr int RG = 256 / C;
  __shared__ float ls[256], lss[256];
  int t = threadIdx.x;
  int col = t % C, rg = t / C;
  float s = 0.f, ss = 0.f;
  for (size_t row = (size_t)blockIdx.x * RG + rg; row < (size_t)nrows; row += (size_t)gridDim.x * RG) {
    float v = y[row * C + col];
    s += v;
    ss += v * v;
  }
  ls[t] = s; lss[t] = ss;
  __syncthreads();
  if (rg == 0) {
    for (int g = 1; g < RG; g++) { s += ls[g * C + col]; ss += lss[g * C + col]; }
    atomicAdd(&sum[col], s);
    atomicAdd(&ssq[col], ss);
  }
}

__global__ void bn_finalize_kernel(const float* __restrict__ sum, const float* __restrict__ ssq,
                                   const float* __restrict__ g, const float* __restrict__ be,
                                   int ncols, float inv_n,
                                   float* __restrict__ scale, float* __restrict__ shift) {
  int t = threadIdx.x;
  if (t < ncols) {
    float m = sum[t] * inv_n;
    float v = ssq[t] * inv_n - m * m;   // biased variance, as torch BN training-mode
    float rstd = rsqrtf(v + BN_EPS);
    float sc = g[t] * rstd;
    scale[t] = sc;
    shift[t] = be[t] - m * sc;
  }
}

// y2 = relu(BN1(y1)) @ W2 + b2
__global__ __launch_bounds__(256) void cls2_kernel(
    const float* __restrict__ y1, const float* __restrict__ scale1,
    const float* __restrict__ shift1, const float* __restrict__ W2,
    const float* __restrict__ b2, float* __restrict__ y2) {
  int r = blockIdx.x * 256 + threadIdx.x;
  if (r >= ELc) return;
  const float* xr = y1 + (size_t)r * HD;
  float acc[32];
#pragma unroll
  for (int h = 0; h < 32; h++) acc[h] = b2[h];
#pragma unroll 2
  for (int k = 0; k < 64; k += 4) {
    float4 v = *(const float4*)(xr + k);
    float x0 = fmaxf(v.x * scale1[k + 0] + shift1[k + 0], 0.f);
    float x1 = fmaxf(v.y * scale1[k + 1] + shift1[k + 1], 0.f);
    float x2 = fmaxf(v.z * scale1[k + 2] + shift1[k + 2], 0.f);
    float x3 = fmaxf(v.w * scale1[k + 3] + shift1[k + 3], 0.f);
#pragma unroll
    for (int h = 0; h < 32; h++) {
      acc[h] = fmaf(x0, W2[(k + 0) * 32 + h], acc[h]);
      acc[h] = fmaf(x1, W2[(k + 1) * 32 + h], acc[h]);
      acc[h] = fmaf(x2, W2[(k + 2) * 32 + h], acc[h]);
      acc[h] = fmaf(x3, W2[(k + 3) * 32 + h], acc[h]);
    }
  }
#pragma unroll
  for (int h = 0; h < 32; h += 4)
    *(float4*)(y2 + (size_t)r * 32 + h) = make_float4(acc[h], acc[h + 1], acc[h + 2], acc[h + 3]);
}

// out = relu(BN2(y2)) @ W3 + b3
__global__ void cls3_kernel(const float* __restrict__ y2, const float* __restrict__ scale2,
                            const float* __restrict__ shift2, const float* __restrict__ W3,
                            const float* __restrict__ b3, float* __restrict__ outp) {
  int r = blockIdx.x * 256 + threadIdx.x;
  if (r >= ELc) return;
  float s = b3[0];
#pragma unroll
  for (int j = 0; j < 32; j++) {
    float v = y2[(size_t)r * 32 + j];
    v = fmaxf(v * scale2[j] + shift2[j], 0.f);
    s += v * W3[j];
  }
  outp[r] = s;
}

}  // namespace

extern "C" void kernel_launch(void* const* d_in, const int* in_sizes, int n_in,
                              void* d_out, int out_size, void* d_ws, size_t ws_size,
                              hipStream_t stream) {
  const int*   n_id    = (const int*)d_in[0];
  const float* movie_x = (const float*)d_in[1];
  const int*   eu      = (const int*)d_in[2];
  const int*   em      = (const int*)d_in[3];
  const int*   lu      = (const int*)d_in[4];
  const int*   lm      = (const int*)d_in[5];
  const float* uemb    = (const float*)d_in[6];
  const float* Wl_um   = (const float*)d_in[7];
  const float* b_um    = (const float*)d_in[8];
  const float* Wr_um   = (const float*)d_in[9];
  const float* Wl_mu   = (const float*)d_in[10];
  const float* b_mu    = (const float*)d_in[11];
  const float* Wr_mu   = (const float*)d_in[12];
  const float* puW     = (const float*)d_in[13];
  const float* pub     = (const float*)d_in[14];
  const float* pmW     = (const float*)d_in[15];
  const float* pmb     = (const float*)d_in[16];
  const float* W1      = (const float*)d_in[17];
  const float* b1      = (const float*)d_in[18];
  const float* g1      = (const float*)d_in[19];
  const float* be1     = (const float*)d_in[20];
  const float* W2      = (const float*)d_in[21];
  const float* b2      = (const float*)d_in[22];
  const float* g2      = (const float*)d_in[23];
  const float* be2     = (const float*)d_in[24];
  const float* W3      = (const float*)d_in[25];
  const float* b3      = (const float*)d_in[26];
  float* outp = (float*)d_out;

  float* ws = (float*)d_ws;
  size_t o = 0;
  float* xu0    = ws + o; o += (size_t)NUc * HD;        // 6.40M f
  float* outs_u = ws + o; o += (size_t)NUc * NL * HD;   // 19.20M f
  float* outs_m = ws + o; o += (size_t)NMc * NL * HD;   //  3.84M f
  float* agg_u  = ws + o; o += (size_t)NUc * HD;        //  6.40M f
  float* agg_m  = ws + o; o += (size_t)NMc * HD;        //  1.28M f (conv region = 37.12M f)
  float* y1 = ws;  // [EL][64] = 32M f, overlaps conv region (dead before cls1)
  float* y2     = ws + o; o += (size_t)ELc * 32;        // 16.00M f
  float* h_u    = ws + o; o += (size_t)NUc * HD;
  float* h_m    = ws + o; o += (size_t)NMc * HD;
  int* ssrc_u = (int*)(ws + o); o += NE;
  int* ssrc_m = (int*)(ws + o); o += NE;
  int* cnt_u  = (int*)(ws + o); o += NUc;
  int* cnt_m  = (int*)(ws + o); o += NMc;
  int* offs_u = (int*)(ws + o); o += NUc + 64;
  int* offs_m = (int*)(ws + o); o += NMc + 64;
  int* cur_u  = (int*)(ws + o); o += NUc;
  int* cur_m  = (int*)(ws + o); o += NMc;
  float* stats = ws + o; o += 512;
  if (ws_size < o * sizeof(float)) return;  // ws too small -> leave zeros (diagnostic)

  float* sum1 = stats,        *ssq1 = stats + 64;
  float* sum2 = stats + 128,  *ssq2 = stats + 160;
  float* scale1 = stats + 192, *shift1 = stats + 256;
  float* scale2 = stats + 320, *shift2 = stats + 352;

  hipMemsetAsync(cnt_u, 0, NUc * sizeof(int), stream);
  hipMemsetAsync(cnt_m, 0, NMc * sizeof(int), stream);
  hipMemsetAsync(stats, 0, 192 * sizeof(float), stream);

  int eb = (NE + 255) / 256;
  count_kernel<<<eb, 256, 0, stream>>>(eu, em, cnt_u, cnt_m);
  scan_kernel<<<1, 1024, 0, stream>>>(cnt_u, NUc, offs_u);
  scan_kernel<<<1, 1024, 0, stream>>>(cnt_m, NMc, offs_m);
  hipMemcpyAsync(cur_u, offs_u, NUc * sizeof(int), hipMemcpyDeviceToDevice, stream);
  hipMemcpyAsync(cur_m, offs_m, NMc * sizeof(int), hipMemcpyDeviceToDevice, stream);
  binscatter_kernel<<<eb, 256, 0, stream>>>(eu, em, cur_u, cur_m, ssrc_u, ssrc_m);
  gather_xu0_kernel<<<(NUc * 16 + 255) / 256, 256, 0, stream>>>(n_id, uemb, xu0);

  for (int i = 0; i < NL; i++) {
    const float* xu_prev = (i == 0) ? xu0 : (outs_u + (size_t)(i - 1) * HD);
    const float* xm_prev = (i == 0) ? movie_x : (outs_m + (size_t)(i - 1) * HD);
    int su = (i == 0) ? HD : NL * HD;
    int sm = (i == 0) ? HD : NL * HD;
    aggregate_kernel<<<(NMc * 64 + 255) / 256, 256, 0, stream>>>(offs_m, ssrc_m, xu_prev, su, agg_m, NMc);
    aggregate_kernel<<<(NUc * 64 + 255) / 256, 256, 0, stream>>>(offs_u, ssrc_u, xm_prev, sm, agg_u, NUc);
    sage_kernel<<<(NMc + 255) / 256, 256, 0, stream>>>(
        NMc, agg_m, xm_prev, sm,
        Wl_um + (size_t)i * HD * HD, Wr_um + (size_t)i * HD * HD, b_um + (size_t)i * HD,
        outs_m + (size_t)i * HD, NL * HD);
    sage_kernel<<<(NUc + 255) / 256, 256, 0, stream>>>(
        NUc, agg_u, xu_prev, su,
        Wl_mu + (size_t)i * HD * HD, Wr_mu + (size_t)i * HD * HD, b_mu + (size_t)i * HD,
        outs_u + (size_t)i * HD, NL * HD);
  }

  proj_kernel<<<(NUc + 255) / 256, 256, 0, stream>>>(NUc, outs_u, puW, pub, h_u);
  proj_kernel<<<(NMc + 255) / 256, 256, 0, stream>>>(NMc, outs_m, pmW, pmb, h_m);

  int lb = (ELc + 255) / 256;
  cls1_kernel<<<lb, 256, 0, stream>>>(h_u, h_m, lu, lm, W1, b1, y1);
  stats_kernel<64><<<1024, 256, 0, stream>>>(y1, ELc, sum1, ssq1);
  bn_finalize_kernel<<<1, 64, 0, stream>>>(sum1, ssq1, g1, be1, 64, 1.f / ELc, scale1, shift1);
  cls2_kernel<<<lb, 256, 0, stream>>>(y1, scale1, shift1, W2, b2, y2);
  stats_kernel<32><<<1024, 256, 0, stream>>>(y2, ELc, sum2, ssq2);
  bn_finalize_kernel<<<1, 64, 0, stream>>>(sum2, ssq2, g2, be2, 32, 1.f / ELc, scale2, shift2);
  cls3_kernel<<<lb, 256, 0, stream>>>(y2, scale2, shift2, W3, b3, outp);
}

// Round 5
// 1349.558 us; speedup vs baseline: 1.6769x; 1.1664x over previous
//
#include <hip/hip_runtime.h>

// Hetero GraphSAGE (3 layers, users<->movies) + JK-cat projection + BN-MLP edge scorer.
// R5 (on top of R4's thread-per-row GEMMs):
//   - binscatter partitioned into 4 sequential dst-range passes so the 2MB scatter
//     window stays L2-resident (R4: 132MB HBM writes for 8MB payload, 16x amplification).
//   - single-block scans replaced by 3-phase parallel scan (partials -> scan -> emit),
//     which also emits the `cur` copies (removes 2 memcpy launches).

namespace {

constexpr int NUc = 100000;
constexpr int NMc = 20000;
constexpr int HD  = 64;
constexpr int NE  = 1000000;
constexpr int ELc = 500000;
constexpr int NL  = 3;
constexpr float BN_EPS = 1e-5f;

constexpr int SCAN_ELEMS = 512;                       // elements per scan block
constexpr int NB_U = (NUc + SCAN_ELEMS - 1) / SCAN_ELEMS;  // 196
constexpr int NB_M = (NMc + SCAN_ELEMS - 1) / SCAN_ELEMS;  // 40
constexpr int NPASS = 4;                              // binscatter dst-range passes

// ---------------- CSR build ----------------

__global__ void count_kernel(const int* __restrict__ eu, const int* __restrict__ em,
                             int* __restrict__ cu, int* __restrict__ cm) {
  int t = blockIdx.x * 256 + threadIdx.x;
  if (t < NE) {
    atomicAdd(&cu[eu[t]], 1);
    atomicAdd(&cm[em[t]], 1);
  }
}

// phase A: per-block (512-elem chunk) totals
__global__ __launch_bounds__(256) void scanA_kernel(const int* __restrict__ cnt, int n,
                                                    int* __restrict__ part) {
  __shared__ int red[256];
  int t = threadIdx.x;
  int base = blockIdx.x * SCAN_ELEMS;
  int s = 0;
  int i0 = base + 2 * t, i1 = i0 + 1;
  if (i0 < n) s += cnt[i0];
  if (i1 < n) s += cnt[i1];
  red[t] = s;
  __syncthreads();
  for (int d = 128; d > 0; d >>= 1) {
    if (t < d) red[t] += red[t + d];
    __syncthreads();
  }
  if (t == 0) part[blockIdx.x] = red[0];
}

// phase B: exclusive scan of both partial arrays (block 0: users, block 1: movies)
__global__ __launch_bounds__(256) void scanB_kernel(int* __restrict__ part_u, int nbu,
                                                    int* __restrict__ part_m, int nbm) {
  __shared__ int s[256];
  int* part = (blockIdx.x == 0) ? part_u : part_m;
  int nb    = (blockIdx.x == 0) ? nbu : nbm;
  int t = threadIdx.x;
  s[t] = (t < nb) ? part[t] : 0;
  __syncthreads();
  for (int d = 1; d < 256; d <<= 1) {
    int v  = s[t];
    int vp = (t >= d) ? s[t - d] : 0;
    __syncthreads();
    s[t] = v + vp;
    __syncthreads();
  }
  if (t < nb) part[t] = (t > 0) ? s[t - 1] : 0;   // exclusive
}

// phase C: rescan chunk + block prefix -> offs (and cur copy); also writes offs[n]
__global__ __launch_bounds__(256) void scanC_kernel(const int* __restrict__ cnt, int n,
                                                    const int* __restrict__ part,
                                                    int* __restrict__ offs,
                                                    int* __restrict__ cur) {
  __shared__ int s[256];
  int t = threadIdx.x;
  int base = blockIdx.x * SCAN_ELEMS;
  int i0 = base + 2 * t, i1 = i0 + 1;
  int a0 = (i0 < n) ? cnt[i0] : 0;
  int a1 = (i1 < n) ? cnt[i1] : 0;
  s[t] = a0 + a1;
  __syncthreads();
  for (int d = 1; d < 256; d <<= 1) {
    int v  = s[t];
    int vp = (t >= d) ? s[t - d] : 0;
    __syncthreads();
    s[t] = v + vp;
    __syncthreads();
  }
  int run = part[blockIdx.x] + ((t > 0) ? s[t - 1] : 0);
  if (i0 < n) { offs[i0] = run; cur[i0] = run; if (i0 == n - 1) offs[n] = run + a0; }
  run += a0;
  if (i1 < n) { offs[i1] = run; cur[i1] = run; if (i1 == n - 1) offs[n] = run + a1; }
}

// one dst-range pass of the bucket scatter; window stays L2-resident per pass
__global__ void binscatter_pass_kernel(const int* __restrict__ eu, const int* __restrict__ em,
                                       int* __restrict__ cu, int* __restrict__ cm,
                                       int* __restrict__ su, int* __restrict__ sm,
                                       int ulo, int uhi, int mlo, int mhi) {
  int t = blockIdx.x * 256 + threadIdx.x;
  if (t < NE) {
    int u = eu[t], m = em[t];
    if (u >= ulo && u < uhi) { int pu = atomicAdd(&cu[u], 1); su[pu] = m; }
    if (m >= mlo && m < mhi) { int pm = atomicAdd(&cm[m], 1); sm[pm] = u; }
  }
}

__global__ void gather_xu0_kernel(const int* __restrict__ n_id, const float* __restrict__ emb,
                                  float* __restrict__ xu0) {
  int t = blockIdx.x * 256 + threadIdx.x;
  if (t < NUc * 16) {
    int n = t >> 4, c = t & 15;
    float4 v = *(const float4*)(emb + (size_t)n_id[n] * HD + c * 4);
    *(float4*)(xu0 + (size_t)n * HD + c * 4) = v;
  }
}

// ---------------- mean aggregation: one wave per dst node, lane = feature ----------------

__global__ void aggregate_kernel(const int* __restrict__ offs, const int* __restrict__ ssrc,
                                 const float* __restrict__ xsrc, int xstride,
                                 float* __restrict__ agg, int ndst) {
  int gid  = blockIdx.x * 256 + threadIdx.x;
  int w    = gid >> 6;
  int lane = gid & 63;
  if (w >= ndst) return;
  int s0 = offs[w], s1 = offs[w + 1];
  float acc = 0.f;
  int i = s0;
  for (; i + 4 <= s1; i += 4) {
    int a0 = ssrc[i], a1 = ssrc[i + 1], a2 = ssrc[i + 2], a3 = ssrc[i + 3];
    acc += xsrc[(size_t)a0 * xstride + lane] + xsrc[(size_t)a1 * xstride + lane] +
           xsrc[(size_t)a2 * xstride + lane] + xsrc[(size_t)a3 * xstride + lane];
  }
  for (; i < s1; i++) acc += xsrc[(size_t)ssrc[i] * xstride + lane];
  float inv = 1.f / fmaxf((float)(s1 - s0), 1.f);
  agg[(size_t)w * HD + lane] = acc * inv;
}

// ---------------- thread-per-row GEMM core ----------------

template <int KTOT, int NOUT>
__device__ __forceinline__ void row_mm(const float* __restrict__ x,
                                       const float* __restrict__ W,
                                       float (&acc)[NOUT]) {
#pragma unroll 2
  for (int k = 0; k < KTOT; k += 4) {
    float4 v = *(const float4*)(x + k);
    const float* w = W + k * NOUT;
#pragma unroll
    for (int h = 0; h < NOUT; h++) {
      acc[h] = fmaf(v.x, w[0 * NOUT + h], acc[h]);
      acc[h] = fmaf(v.y, w[1 * NOUT + h], acc[h]);
      acc[h] = fmaf(v.z, w[2 * NOUT + h], acc[h]);
      acc[h] = fmaf(v.w, w[3 * NOUT + h], acc[h]);
    }
  }
}

// out = relu(agg@Wl + x@Wr + b)
__global__ __launch_bounds__(256) void sage_kernel(
    int N, const float* __restrict__ agg,
    const float* __restrict__ xin, int xstride,
    const float* __restrict__ Wl, const float* __restrict__ Wr,
    const float* __restrict__ bias,
    float* __restrict__ out, int ostride) {
  int r = blockIdx.x * 256 + threadIdx.x;
  if (r >= N) return;
  float acc[64];
#pragma unroll
  for (int h = 0; h < 64; h++) acc[h] = bias[h];
  row_mm<64, 64>(agg + (size_t)r * HD, Wl, acc);
  row_mm<64, 64>(xin + (size_t)r * xstride, Wr, acc);
  float* o = out + (size_t)r * ostride;
#pragma unroll
  for (int h = 0; h < 64; h += 4) {
    float4 v;
    v.x = fmaxf(acc[h + 0], 0.f);
    v.y = fmaxf(acc[h + 1], 0.f);
    v.z = fmaxf(acc[h + 2], 0.f);
    v.w = fmaxf(acc[h + 3], 0.f);
    *(float4*)(o + h) = v;
  }
}

// h = x(JK-cat, stride 192) @ W + b
__global__ __launch_bounds__(256) void proj_kernel(
    int N, const float* __restrict__ xin, const float* __restrict__ W,
    const float* __restrict__ bias, float* __restrict__ out) {
  int r = blockIdx.x * 256 + threadIdx.x;
  if (r >= N) return;
  float acc[64];
#pragma unroll
  for (int h = 0; h < 64; h++) acc[h] = bias[h];
  row_mm<192, 64>(xin + (size_t)r * (NL * HD), W, acc);
  float* o = out + (size_t)r * HD;
#pragma unroll
  for (int h = 0; h < 64; h += 4)
    *(float4*)(o + h) = make_float4(acc[h], acc[h + 1], acc[h + 2], acc[h + 3]);
}

// y1 = cat(h_u[lu], h_m[lm]) @ W1 + b1
__global__ __launch_bounds__(256) void cls1_kernel(
    const float* __restrict__ hu, const float* __restrict__ hm,
    const int* __restrict__ lu, const int* __restrict__ lm,
    const float* __restrict__ W1, const float* __restrict__ b1,
    float* __restrict__ y1) {
  int r = blockIdx.x * 256 + threadIdx.x;
  if (r >= ELc) return;
  float acc[64];
#pragma unroll
  for (int h = 0; h < 64; h++) acc[h] = b1[h];
  row_mm<64, 64>(hu + (size_t)lu[r] * HD, W1, acc);
  row_mm<64, 64>(hm + (size_t)lm[r] * HD, W1 + 64 * 64, acc);
  float* o = y1 + (size_t)r * HD;
#pragma unroll
  for (int h = 0; h < 64; h += 4)
    *(float4*)(o + h) = make_float4(acc[h], acc[h + 1], acc[h + 2], acc[h + 3]);
}

// column sums/sumsq of y [nrows x C]
template <int C>
__global__ __launch_bounds__(256) void stats_kernel(const float* __restrict__ y, int nrows,
                                                    float* __restrict__ sum,
                                                    float* __restrict__ ssq) {
  constexpr int RG = 256 / C;
  __shared__ float ls[256], lss[256];
  int t = threadIdx.x;
  int col = t % C, rg = t / C;
  float s = 0.f, ss = 0.f;
  for (size_t row = (size_t)blockIdx.x * RG + rg; row < (size_t)nrows; row += (size_t)gridDim.x * RG) {
    float v = y[row * C + col];
    s += v;
    ss += v * v;
  }
  ls[t] = s; lss[t] = ss;
  __syncthreads();
  if (rg == 0) {
    for (int g = 1; g < RG; g++) { s += ls[g * C + col]; ss += lss[g * C + col]; }
    atomicAdd(&sum[col], s);
    atomicAdd(&ssq[col], ss);
  }
}

__global__ void bn_finalize_kernel(const float* __restrict__ sum, const float* __restrict__ ssq,
                                   const float* __restrict__ g, const float* __restrict__ be,
                                   int ncols, float inv_n,
                                   float* __restrict__ scale, float* __restrict__ shift) {
  int t = threadIdx.x;
  if (t < ncols) {
    float m = sum[t] * inv_n;
    float v = ssq[t] * inv_n - m * m;   // biased variance, as torch BN training-mode
    float rstd = rsqrtf(v + BN_EPS);
    float sc = g[t] * rstd;
    scale[t] = sc;
    shift[t] = be[t] - m * sc;
  }
}

// y2 = relu(BN1(y1)) @ W2 + b2
__global__ __launch_bounds__(256) void cls2_kernel(
    const float* __restrict__ y1, const float* __restrict__ scale1,
    const float* __restrict__ shift1, const float* __restrict__ W2,
    const float* __restrict__ b2, float* __restrict__ y2) {
  int r = blockIdx.x * 256 + threadIdx.x;
  if (r >= ELc) return;
  const float* xr = y1 + (size_t)r * HD;
  float acc[32];
#pragma unroll
  for (int h = 0; h < 32; h++) acc[h] = b2[h];
#pragma unroll 2
  for (int k = 0; k < 64; k += 4) {
    float4 v = *(const float4*)(xr + k);
    float x0 = fmaxf(v.x * scale1[k + 0] + shift1[k + 0], 0.f);
    float x1 = fmaxf(v.y * scale1[k + 1] + shift1[k + 1], 0.f);
    float x2 = fmaxf(v.z * scale1[k + 2] + shift1[k + 2], 0.f);
    float x3 = fmaxf(v.w * scale1[k + 3] + shift1[k + 3], 0.f);
#pragma unroll
    for (int h = 0; h < 32; h++) {
      acc[h] = fmaf(x0, W2[(k + 0) * 32 + h], acc[h]);
      acc[h] = fmaf(x1, W2[(k + 1) * 32 + h], acc[h]);
      acc[h] = fmaf(x2, W2[(k + 2) * 32 + h], acc[h]);
      acc[h] = fmaf(x3, W2[(k + 3) * 32 + h], acc[h]);
    }
  }
#pragma unroll
  for (int h = 0; h < 32; h += 4)
    *(float4*)(y2 + (size_t)r * 32 + h) = make_float4(acc[h], acc[h + 1], acc[h + 2], acc[h + 3]);
}

// out = relu(BN2(y2)) @ W3 + b3
__global__ void cls3_kernel(const float* __restrict__ y2, const float* __restrict__ scale2,
                            const float* __restrict__ shift2, const float* __restrict__ W3,
                            const float* __restrict__ b3, float* __restrict__ outp) {
  int r = blockIdx.x * 256 + threadIdx.x;
  if (r >= ELc) return;
  float s = b3[0];
#pragma unroll
  for (int j = 0; j < 32; j++) {
    float v = y2[(size_t)r * 32 + j];
    v = fmaxf(v * scale2[j] + shift2[j], 0.f);
    s += v * W3[j];
  }
  outp[r] = s;
}

}  // namespace

extern "C" void kernel_launch(void* const* d_in, const int* in_sizes, int n_in,
                              void* d_out, int out_size, void* d_ws, size_t ws_size,
                              hipStream_t stream) {
  const int*   n_id    = (const int*)d_in[0];
  const float* movie_x = (const float*)d_in[1];
  const int*   eu      = (const int*)d_in[2];
  const int*   em      = (const int*)d_in[3];
  const int*   lu      = (const int*)d_in[4];
  const int*   lm      = (const int*)d_in[5];
  const float* uemb    = (const float*)d_in[6];
  const float* Wl_um   = (const float*)d_in[7];
  const float* b_um    = (const float*)d_in[8];
  const float* Wr_um   = (const float*)d_in[9];
  const float* Wl_mu   = (const float*)d_in[10];
  const float* b_mu    = (const float*)d_in[11];
  const float* Wr_mu   = (const float*)d_in[12];
  const float* puW     = (const float*)d_in[13];
  const float* pub     = (const float*)d_in[14];
  const float* pmW     = (const float*)d_in[15];
  const float* pmb     = (const float*)d_in[16];
  const float* W1      = (const float*)d_in[17];
  const float* b1      = (const float*)d_in[18];
  const float* g1      = (const float*)d_in[19];
  const float* be1     = (const float*)d_in[20];
  const float* W2      = (const float*)d_in[21];
  const float* b2      = (const float*)d_in[22];
  const float* g2      = (const float*)d_in[23];
  const float* be2     = (const float*)d_in[24];
  const float* W3      = (const float*)d_in[25];
  const float* b3      = (const float*)d_in[26];
  float* outp = (float*)d_out;

  float* ws = (float*)d_ws;
  size_t o = 0;
  float* xu0    = ws + o; o += (size_t)NUc * HD;        // 6.40M f
  float* outs_u = ws + o; o += (size_t)NUc * NL * HD;   // 19.20M f
  float* outs_m = ws + o; o += (size_t)NMc * NL * HD;   //  3.84M f
  float* agg_u  = ws + o; o += (size_t)NUc * HD;        //  6.40M f
  float* agg_m  = ws + o; o += (size_t)NMc * HD;        //  1.28M f (conv region = 37.12M f)
  float* y1 = ws;  // [EL][64] = 32M f, overlaps conv region (dead before cls1)
  float* y2     = ws + o; o += (size_t)ELc * 32;        // 16.00M f
  float* h_u    = ws + o; o += (size_t)NUc * HD;
  float* h_m    = ws + o; o += (size_t)NMc * HD;
  int* ssrc_u = (int*)(ws + o); o += NE;
  int* ssrc_m = (int*)(ws + o); o += NE;
  int* cnt_u  = (int*)(ws + o); o += NUc;
  int* cnt_m  = (int*)(ws + o); o += NMc;
  int* offs_u = (int*)(ws + o); o += NUc + 64;
  int* offs_m = (int*)(ws + o); o += NMc + 64;
  int* cur_u  = (int*)(ws + o); o += NUc;
  int* cur_m  = (int*)(ws + o); o += NMc;
  int* part_u = (int*)(ws + o); o += 256;
  int* part_m = (int*)(ws + o); o += 256;
  float* stats = ws + o; o += 512;
  if (ws_size < o * sizeof(float)) return;  // ws too small -> leave zeros (diagnostic)

  float* sum1 = stats,        *ssq1 = stats + 64;
  float* sum2 = stats + 128,  *ssq2 = stats + 160;
  float* scale1 = stats + 192, *shift1 = stats + 256;
  float* scale2 = stats + 320, *shift2 = stats + 352;

  hipMemsetAsync(cnt_u, 0, NUc * sizeof(int), stream);
  hipMemsetAsync(cnt_m, 0, NMc * sizeof(int), stream);
  hipMemsetAsync(stats, 0, 192 * sizeof(float), stream);

  int eb = (NE + 255) / 256;
  count_kernel<<<eb, 256, 0, stream>>>(eu, em, cnt_u, cnt_m);
  scanA_kernel<<<NB_U, 256, 0, stream>>>(cnt_u, NUc, part_u);
  scanA_kernel<<<NB_M, 256, 0, stream>>>(cnt_m, NMc, part_m);
  scanB_kernel<<<2, 256, 0, stream>>>(part_u, NB_U, part_m, NB_M);
  scanC_kernel<<<NB_U, 256, 0, stream>>>(cnt_u, NUc, part_u, offs_u, cur_u);
  scanC_kernel<<<NB_M, 256, 0, stream>>>(cnt_m, NMc, part_m, offs_m, cur_m);
  for (int p = 0; p < NPASS; p++) {
    binscatter_pass_kernel<<<eb, 256, 0, stream>>>(
        eu, em, cur_u, cur_m, ssrc_u, ssrc_m,
        p * (NUc / NPASS), (p + 1) * (NUc / NPASS),
        p * (NMc / NPASS), (p + 1) * (NMc / NPASS));
  }
  gather_xu0_kernel<<<(NUc * 16 + 255) / 256, 256, 0, stream>>>(n_id, uemb, xu0);

  for (int i = 0; i < NL; i++) {
    const float* xu_prev = (i == 0) ? xu0 : (outs_u + (size_t)(i - 1) * HD);
    const float* xm_prev = (i == 0) ? movie_x : (outs_m + (size_t)(i - 1) * HD);
    int su = (i == 0) ? HD : NL * HD;
    int sm = (i == 0) ? HD : NL * HD;
    aggregate_kernel<<<(NMc * 64 + 255) / 256, 256, 0, stream>>>(offs_m, ssrc_m, xu_prev, su, agg_m, NMc);
    aggregate_kernel<<<(NUc * 64 + 255) / 256, 256, 0, stream>>>(offs_u, ssrc_u, xm_prev, sm, agg_u, NUc);
    sage_kernel<<<(NMc + 255) / 256, 256, 0, stream>>>(
        NMc, agg_m, xm_prev, sm,
        Wl_um + (size_t)i * HD * HD, Wr_um + (size_t)i * HD * HD, b_um + (size_t)i * HD,
        outs_m + (size_t)i * HD, NL * HD);
    sage_kernel<<<(NUc + 255) / 256, 256, 0, stream>>>(
        NUc, agg_u, xu_prev, su,
        Wl_mu + (size_t)i * HD * HD, Wr_mu + (size_t)i * HD * HD, b_mu + (size_t)i * HD,
        outs_u + (size_t)i * HD, NL * HD);
  }

  proj_kernel<<<(NUc + 255) / 256, 256, 0, stream>>>(NUc, outs_u, puW, pub, h_u);
  proj_kernel<<<(NMc + 255) / 256, 256, 0, stream>>>(NMc, outs_m, pmW, pmb, h_m);

  int lb = (ELc + 255) / 256;
  cls1_kernel<<<lb, 256, 0, stream>>>(h_u, h_m, lu, lm, W1, b1, y1);
  stats_kernel<64><<<1024, 256, 0, stream>>>(y1, ELc, sum1, ssq1);
  bn_finalize_kernel<<<1, 64, 0, stream>>>(sum1, ssq1, g1, be1, 64, 1.f / ELc, scale1, shift1);
  cls2_kernel<<<lb, 256, 0, stream>>>(y1, scale1, shift1, W2, b2, y2);
  stats_kernel<32><<<1024, 256, 0, stream>>>(y2, ELc, sum2, ssq2);
  bn_finalize_kernel<<<1, 64, 0, stream>>>(sum2, ssq2, g2, be2, 32, 1.f / ELc, scale2, shift2);
  cls3_kernel<<<lb, 256, 0, stream>>>(y2, scale2, shift2, W3, b3, outp);
}